// Round 6
// baseline (163.993 us; speedup 1.0000x reference)
//
#include <hip/hip_runtime.h>
#include <hip/hip_bf16.h>

// ---------------- problem constants ----------------------------------------
// B=2, T=2, C=256, heads=8, levels=4, points=4, head_dim=32
// level shapes: (64,64),(32,32),(16,16),(8,8); Bt=4
// rows per level (Bt*HW): 16384, 4096, 1024, 256 ; total NR=21760
#define NR 21760

typedef short short8 __attribute__((ext_vector_type(8)));
typedef float f32x4 __attribute__((ext_vector_type(4)));

__device__ __forceinline__ int level_of_row(int R) {
    if (R < 16384) return 0;
    if (R < 20480) return 1;
    if (R < 21504) return 2;
    return 3;
}

// ---------------- K1: pack all levels [B,C,H,W,T] -> XPb[row][c] (bf16) ----
__global__ __launch_bounds__(256) void pack_all_kernel(const float* __restrict__ f0,
                                                       const float* __restrict__ f1,
                                                       const float* __restrict__ f2,
                                                       const float* __restrict__ f3,
                                                       __hip_bfloat16* __restrict__ XP) {
    int bx = blockIdx.x;
    const float* f; int nj, Wl, rowbase, rel;
    if (bx < 1024)      { f = f0; nj = 128; Wl = 64; rowbase = 0;     rel = bx; }
    else if (bx < 1280) { f = f1; nj = 32;  Wl = 32; rowbase = 16384; rel = bx - 1024; }
    else if (bx < 1344) { f = f2; nj = 8;   Wl = 16; rowbase = 20480; rel = bx - 1280; }
    else                { f = f3; nj = 2;   Wl = 8;  rowbase = 21504; rel = bx - 1344; }
    const int HW = Wl * Wl;
    const int HWT = HW * 2;
    const int j0 = (rel % nj) * 64;
    const int c0 = ((rel / nj) & 3) * 64;
    const int b  = rel / (nj * 4);
    __shared__ float tile[64][65];
    {
        const int tj = threadIdx.x & 63;
        const int tcb = threadIdx.x >> 6;
        const float* fb = f + (size_t)(b * 256 + c0) * HWT + j0;
#pragma unroll
        for (int i = 0; i < 16; ++i) {
            int cl = tcb + i * 4;
            tile[cl][tj] = fb[(size_t)cl * HWT + tj];
        }
    }
    __syncthreads();
    {
        const int tc = threadIdx.x & 63;
        const int tjb = threadIdx.x >> 6;
#pragma unroll
        for (int i = 0; i < 16; ++i) {
            int jl = tjb + i * 4;
            int j = j0 + jl;
            int p = j >> 1, t = j & 1;
            int row = rowbase + (b * 2 + t) * HW + p;
            XP[(size_t)row * 256 + c0 + tc] = __float2bfloat16(tile[tc][jl]);
        }
    }
}

// ---------------- K2: all weight transposes + bias concat in ONE launch ----
__global__ __launch_bounds__(256) void wtrans_all_kernel(const float* __restrict__ Wq,
                                                         const float* __restrict__ Wv,
                                                         const float* __restrict__ Woff,
                                                         const float* __restrict__ Wattn,
                                                         const float* __restrict__ Wout,
                                                         const float* __restrict__ boff,
                                                         const float* __restrict__ battn,
                                                         __hip_bfloat16* __restrict__ WTvq,
                                                         __hip_bfloat16* __restrict__ WToa,
                                                         __hip_bfloat16* __restrict__ WTout,
                                                         float* __restrict__ bias_oa) {
    __shared__ float t[32][33];
    const int bx = blockIdx.x;
    const int tid = threadIdx.x;
    if (bx == 288) {
        bias_oa[tid] = boff[tid];
        if (tid < 128) bias_oa[256 + tid] = battn[tid];
        return;
    }
    const float* W; __hip_bfloat16* WT; int N; int rel;
    if (bx < 64)       { W = Wv;    WT = WTvq;             N = 256; rel = bx; }
    else if (bx < 128) { W = Wq;    WT = WTvq + 256 * 256; N = 256; rel = bx - 64; }
    else if (bx < 192) { W = Woff;  WT = WToa;             N = 256; rel = bx - 128; }
    else if (bx < 224) { W = Wattn; WT = WToa + 256 * 256; N = 128; rel = bx - 192; }
    else               { W = Wout;  WT = WTout;            N = 256; rel = bx - 224; }
    const int K = 256;
    const int ntiles = N >> 5;
    const int n0 = (rel % ntiles) * 32, k0 = (rel / ntiles) * 32;
    const int c = tid & 31, r = tid >> 5;
#pragma unroll
    for (int i = 0; i < 4; ++i)
        t[r + 8 * i][c] = W[(size_t)(k0 + r + 8 * i) * N + n0 + c];
    __syncthreads();
#pragma unroll
    for (int i = 0; i < 4; ++i)
        WT[(size_t)(n0 + r + 8 * i) * K + k0 + c] = __float2bfloat16(t[c][r + 8 * i]);
}

// ---------------- K3: bf16 MFMA GEMM  C = A[M,K] @ BT[N,K]^T + bias --------
// OUTMODE: 0 = f32 single ; 1 = dual bf16 split at col 256 ; 2 = f32 scatter
template <int OUTMODE>
__global__ __launch_bounds__(256) void gemm_mfma(const __hip_bfloat16* __restrict__ A,
                                                 const __hip_bfloat16* __restrict__ BT,
                                                 const float* __restrict__ bias,
                                                 const float* __restrict__ bias2,
                                                 void* __restrict__ Cout,
                                                 void* __restrict__ Cout2,
                                                 int M, int N, int K) {
    __shared__ __align__(16) __hip_bfloat16 As[64][72];
    __shared__ __align__(16) __hip_bfloat16 Bs[64][72];
    const int m0 = blockIdx.x * 64;
    const int n0 = blockIdx.y * 64;
    const int w = threadIdx.x >> 6;
    const int lane = threadIdx.x & 63;
    const int wm = (w >> 1) * 32;
    const int wn = (w & 1) * 32;
    const int fr = lane & 15;
    const int fq = lane >> 4;
    const int srow = threadIdx.x >> 3;
    const int schunk = threadIdx.x & 7;
    f32x4 acc[2][2] = {};

    for (int kt = 0; kt < K; kt += 64) {
        __syncthreads();
#pragma unroll
        for (int i = 0; i < 2; ++i) {
            int r = srow + 32 * i;
            float4 va = *(const float4*)(&A[(size_t)(m0 + r) * K + kt + schunk * 8]);
            *(float4*)(&As[r][schunk * 8]) = va;
            float4 vb = *(const float4*)(&BT[(size_t)(n0 + r) * K + kt + schunk * 8]);
            *(float4*)(&Bs[r][schunk * 8]) = vb;
        }
        __syncthreads();
#pragma unroll
        for (int ks = 0; ks < 2; ++ks) {
            short8 a[2], b[2];
#pragma unroll
            for (int fi = 0; fi < 2; ++fi)
                a[fi] = *(const short8*)(&As[wm + fi * 16 + fr][ks * 32 + fq * 8]);
#pragma unroll
            for (int fj = 0; fj < 2; ++fj)
                b[fj] = *(const short8*)(&Bs[wn + fj * 16 + fr][ks * 32 + fq * 8]);
#pragma unroll
            for (int fi = 0; fi < 2; ++fi)
#pragma unroll
                for (int fj = 0; fj < 2; ++fj)
                    acc[fi][fj] = __builtin_amdgcn_mfma_f32_16x16x32_bf16(
                        a[fi], b[fj], acc[fi][fj], 0, 0, 0);
        }
    }

    if (OUTMODE == 2) {
        const int lvl = level_of_row(m0);
        const int qbase[4]   = {0, 16384, 20480, 21504};
        const int wtab[4]    = {64, 32, 16, 8};
        const size_t obase[4] = {0, 4194304, 5242880, 5505024};
        const int Wl = wtab[lvl];
        const int HW = Wl * Wl;
        float* out = (float*)Cout;
#pragma unroll
        for (int fi = 0; fi < 2; ++fi)
#pragma unroll
            for (int fj = 0; fj < 2; ++fj) {
                int col = n0 + wn + fj * 16 + fr;
                float bb = bias[col];
#pragma unroll
                for (int r = 0; r < 4; ++r) {
                    int row = m0 + wm + fi * 16 + fq * 4 + r;
                    int r2 = row - qbase[lvl];
                    int bt = r2 / HW;
                    int p  = r2 - bt * HW;
                    int b  = bt >> 1, t = bt & 1;
                    int y  = p / Wl, x = p - y * Wl;
                    size_t addr = obase[lvl] +
                        ((((size_t)b * 256 + col) * Wl + y) * Wl + x) * 2 + t;
                    out[addr] = acc[fi][fj][r] + bb;
                }
            }
    } else if (OUTMODE == 1) {
        __hip_bfloat16* dst; const float* bs; int cb;
        if (n0 < 256) { dst = (__hip_bfloat16*)Cout;  bs = bias;  cb = n0; }
        else          { dst = (__hip_bfloat16*)Cout2; bs = bias2; cb = n0 - 256; }
#pragma unroll
        for (int fi = 0; fi < 2; ++fi)
#pragma unroll
            for (int fj = 0; fj < 2; ++fj) {
                int col = cb + wn + fj * 16 + fr;
                float bb = bs[col];
#pragma unroll
                for (int r = 0; r < 4; ++r) {
                    int row = m0 + wm + fi * 16 + fq * 4 + r;
                    dst[(size_t)row * 256 + col] = __float2bfloat16(acc[fi][fj][r] + bb);
                }
            }
    } else {
#pragma unroll
        for (int fi = 0; fi < 2; ++fi)
#pragma unroll
            for (int fj = 0; fj < 2; ++fj) {
                int col = n0 + wn + fj * 16 + fr;
                float bb = bias[col];
#pragma unroll
                for (int r = 0; r < 4; ++r) {
                    int row = m0 + wm + fi * 16 + fq * 4 + r;
                    ((float*)Cout)[(size_t)row * N + col] = acc[fi][fj][r] + bb;
                }
            }
    }
}

// ---------------- K5: sampling: fused softmax + taps + bf16 gather ---------
// Split tap storage: int4 offsets + float4 weights, [q][t][h] layout.
// Read addr = (t*8+h)*16B -> lane h spans banks 4h..4h+3 -> conflict-free.
__device__ __forceinline__ void accum(f32x4& acc, uint2 u, float w) {
    acc[0] = fmaf(w, __uint_as_float(u.x << 16), acc[0]);
    acc[1] = fmaf(w, __uint_as_float(u.x & 0xffff0000u), acc[1]);
    acc[2] = fmaf(w, __uint_as_float(u.y << 16), acc[2]);
    acc[3] = fmaf(w, __uint_as_float(u.y & 0xffff0000u), acc[3]);
}

#define QB 4
__global__ __launch_bounds__(256, 4) void sample_kernel(const __hip_bfloat16* __restrict__ VAL,
                                                        const float* __restrict__ OA,
                                                        __hip_bfloat16* __restrict__ SAMP) {
    __shared__ int4   toff[QB * 16 * 8];   // [q][t(16)][h(8)]
    __shared__ float4 twgt[QB * 16 * 8];
    const int R0 = blockIdx.x * QB;
    const int tid = threadIdx.x;
    const int qbase[4] = {0, 16384, 20480, 21504};
    const int wtab[4]  = {64, 32, 16, 8};

    // ---- phase 1: per-(q,h) softmax over 16 + tap precompute (128 threads) ----
    if (tid < QB * 32) {
        const int qh = tid >> 2, part = tid & 3;   // 4 threads per (q,h), 4 taps each
        const int q = qh >> 3, h = qh & 7;
        const int R = R0 + q;
        const int lq = level_of_row(R);
        const int Wq_ = wtab[lq];
        const int r2 = R - qbase[lq];
        const int bt = r2 / (Wq_ * Wq_);
        const int p  = r2 - bt * (Wq_ * Wq_);
        const float refx = ((p % Wq_) + 0.5f) / (float)Wq_;
        const float refy = ((p / Wq_) + 0.5f) / (float)Wq_;
        const float* oarow = OA + (size_t)R * 384;
        float4 offA = *(const float4*)(oarow + h * 32 + part * 8);
        float4 offB = *(const float4*)(oarow + h * 32 + part * 8 + 4);
        float4 awv  = *(const float4*)(oarow + 256 + h * 16 + part * 4);
        // softmax across the 4-lane group (16 taps of this (q,h))
        float m = fmaxf(fmaxf(awv.x, awv.y), fmaxf(awv.z, awv.w));
        m = fmaxf(m, __shfl_xor(m, 1));
        m = fmaxf(m, __shfl_xor(m, 2));
        float e0 = __expf(awv.x - m), e1 = __expf(awv.y - m);
        float e2 = __expf(awv.z - m), e3 = __expf(awv.w - m);
        float s = e0 + e1 + e2 + e3;
        s += __shfl_xor(s, 1);
        s += __shfl_xor(s, 2);
        const float inv = 1.0f / s;
        const int l = part;                // this thread's 4 taps are all level part
        const int Wl = wtab[l];
        const float invWf = 1.0f / (float)Wl;
        const int base = (qbase[l] + bt * Wl * Wl) * 256;
        float oxy[8] = {offA.x, offA.y, offA.z, offA.w, offB.x, offB.y, offB.z, offB.w};
        float ee[4] = {e0, e1, e2, e3};
#pragma unroll
        for (int i = 0; i < 4; ++i) {
            float ox = oxy[2 * i], oy = oxy[2 * i + 1];
            float aw = ee[i] * inv;
            float lx = fminf(fmaxf(refx + ox * invWf, 0.f), 1.f);
            float ly = fminf(fmaxf(refy + oy * invWf, 0.f), 1.f);
            float px = lx * Wl - 0.5f;
            float py = ly * Wl - 0.5f;
            float x0f = floorf(px), y0f = floorf(py);
            int x0 = (int)x0f, y0 = (int)y0f;
            float wx = px - x0f, wy = py - y0f;
            float vx0 = (x0 >= 0) ? 1.f : 0.f;
            float vx1 = (x0 + 1 <= Wl - 1) ? 1.f : 0.f;
            float vy0 = (y0 >= 0) ? 1.f : 0.f;
            float vy1 = (y0 + 1 <= Wl - 1) ? 1.f : 0.f;
            int x0c = max(x0, 0), x1c = min(x0 + 1, Wl - 1);
            int y0c = max(y0, 0), y1c = min(y0 + 1, Wl - 1);
            int idx = (q * 16 + part * 4 + i) * 8 + h;
            toff[idx] = make_int4(base + (y0c * Wl + x0c) * 256,
                                  base + (y0c * Wl + x1c) * 256,
                                  base + (y1c * Wl + x0c) * 256,
                                  base + (y1c * Wl + x1c) * 256);
            float4 w4;
            w4.x = aw * (1.f - wx) * (1.f - wy) * vx0 * vy0;
            w4.y = aw * wx * (1.f - wy) * vx1 * vy0;
            w4.z = aw * (1.f - wx) * wy * vx0 * vy1;
            w4.w = aw * wx * wy * vx1 * vy1;
            twgt[idx] = w4;
        }
    }
    __syncthreads();

    // ---- phase 2: one wave per query; lane = (head, d4); bf16 uint2 gathers ----
    const int wv = tid >> 6, lane = tid & 63;
    const int h = lane >> 3, d4 = lane & 7;
    const int R = R0 + wv;
    const __hip_bfloat16* vb = VAL + h * 32 + d4 * 4;
    const int4*   to = &toff[wv * 128];
    const float4* tw = &twgt[wv * 128];
    f32x4 acc = {0.f, 0.f, 0.f, 0.f};
#pragma unroll
    for (int t = 0; t < 16; ++t) {
        int4   o  = to[t * 8 + h];
        float4 w4 = tw[t * 8 + h];
        uint2 v00 = *(const uint2*)(vb + o.x);
        uint2 v10 = *(const uint2*)(vb + o.y);
        uint2 v01 = *(const uint2*)(vb + o.z);
        uint2 v11 = *(const uint2*)(vb + o.w);
        accum(acc, v00, w4.x);
        accum(acc, v10, w4.y);
        accum(acc, v01, w4.z);
        accum(acc, v11, w4.w);
    }
    union { ushort u[4]; ushort4 v4; } sa;
#pragma unroll
    for (int i = 0; i < 4; ++i) {
        __hip_bfloat16 ba = __float2bfloat16(acc[i]);
        sa.u[i] = *(ushort*)&ba;
    }
    *(ushort4*)(&SAMP[(size_t)R * 256 + h * 32 + d4 * 4]) = sa.v4;
}

// ---------------- launch ---------------------------------------------------
extern "C" void kernel_launch(void* const* d_in, const int* in_sizes, int n_in,
                              void* d_out, int out_size, void* d_ws, size_t ws_size,
                              hipStream_t stream) {
    (void)in_sizes; (void)n_in; (void)out_size; (void)ws_size;
    const float* f0 = (const float*)d_in[0];
    const float* f1 = (const float*)d_in[1];
    const float* f2 = (const float*)d_in[2];
    const float* f3 = (const float*)d_in[3];
    const float* Wq    = (const float*)d_in[4];
    const float* bq    = (const float*)d_in[5];
    const float* Wv    = (const float*)d_in[6];
    const float* bv    = (const float*)d_in[7];
    const float* Woff  = (const float*)d_in[8];
    const float* boff  = (const float*)d_in[9];
    const float* Wattn = (const float*)d_in[10];
    const float* battn = (const float*)d_in[11];
    const float* Wout  = (const float*)d_in[12];
    const float* bout  = (const float*)d_in[13];
    float* out = (float*)d_out;

    char* w = (char*)d_ws;
    __hip_bfloat16* XPb   = (__hip_bfloat16*)w;   w += (size_t)NR * 256 * 2;
    __hip_bfloat16* Qb    = (__hip_bfloat16*)w;   w += (size_t)NR * 256 * 2;
    __hip_bfloat16* SAMPb = (__hip_bfloat16*)w;   w += (size_t)NR * 256 * 2;
    __hip_bfloat16* VAL   = (__hip_bfloat16*)w;   w += (size_t)NR * 256 * 2;
    float* OA   = (float*)w;                      w += (size_t)NR * 384 * 4;   // [OFF(256)|ATT(128)]
    __hip_bfloat16* WTvq  = (__hip_bfloat16*)w;   w += 512 * 256 * 2;          // [Wv^T | Wq^T]
    __hip_bfloat16* WToa  = (__hip_bfloat16*)w;   w += 384 * 256 * 2;          // [Woff^T | Wattn^T]
    __hip_bfloat16* WTout = (__hip_bfloat16*)w;   w += 256 * 256 * 2;
    float* bias_oa = (float*)w;                   w += 384 * 4;

    // K1: pack all levels (1 launch)
    hipLaunchKernelGGL(pack_all_kernel, dim3(1360), dim3(256), 0, stream, f0, f1, f2, f3, XPb);

    // K2: all weight transposes + bias concat (1 launch)
    hipLaunchKernelGGL(wtrans_all_kernel, dim3(289), dim3(256), 0, stream,
                       Wq, Wv, Woff, Wattn, Wout, boff, battn, WTvq, WToa, WTout, bias_oa);

    // K3a: fused VAL+Q projection (N=512, dual bf16 outputs)
    hipLaunchKernelGGL((gemm_mfma<1>), dim3(NR / 64, 8), dim3(256), 0, stream,
                       XPb, WTvq, bv, bq, (void*)VAL, (void*)Qb, NR, 512, 256);

    // K3b: OFF+ATT projection (N=384, f32)
    hipLaunchKernelGGL((gemm_mfma<0>), dim3(NR / 64, 6), dim3(256), 0, stream,
                       Qb, WToa, bias_oa, nullptr, (void*)OA, nullptr, NR, 384, 256);

    // K5: sampling (fused softmax + taps + bf16 gather)
    hipLaunchKernelGGL(sample_kernel, dim3(NR / QB), dim3(256), 0, stream, VAL, OA, SAMPb);

    // K6: output projection + scatter
    hipLaunchKernelGGL((gemm_mfma<2>), dim3(NR / 64, 4), dim3(256), 0, stream,
                       SAMPb, WTout, bout, nullptr, (void*)out, nullptr, NR, 256, 256);
}

// Round 7
// 114.731 us; speedup vs baseline: 1.4294x; 1.4294x over previous
//
#include <hip/hip_runtime.h>
#include <hip/hip_bf16.h>

// ---------------- problem constants ----------------------------------------
// B=2, T=2, C=256, heads=8, levels=4, points=4, head_dim=32
// level shapes: (64,64),(32,32),(16,16),(8,8); Bt=4
// rows per level (Bt*HW): 16384, 4096, 1024, 256 ; total NR=21760
#define NR 21760

typedef short short8 __attribute__((ext_vector_type(8)));
typedef float f32x4 __attribute__((ext_vector_type(4)));

__device__ __forceinline__ int level_of_row(int R) {
    if (R < 16384) return 0;
    if (R < 20480) return 1;
    if (R < 21504) return 2;
    return 3;
}

// ---------------- K1: pack all levels [B,C,H,W,T] -> XPb[row][c] (bf16) ----
__global__ __launch_bounds__(256) void pack_all_kernel(const float* __restrict__ f0,
                                                       const float* __restrict__ f1,
                                                       const float* __restrict__ f2,
                                                       const float* __restrict__ f3,
                                                       __hip_bfloat16* __restrict__ XP) {
    int bx = blockIdx.x;
    const float* f; int nj, Wl, rowbase, rel;
    if (bx < 1024)      { f = f0; nj = 128; Wl = 64; rowbase = 0;     rel = bx; }
    else if (bx < 1280) { f = f1; nj = 32;  Wl = 32; rowbase = 16384; rel = bx - 1024; }
    else if (bx < 1344) { f = f2; nj = 8;   Wl = 16; rowbase = 20480; rel = bx - 1280; }
    else                { f = f3; nj = 2;   Wl = 8;  rowbase = 21504; rel = bx - 1344; }
    const int HW = Wl * Wl;
    const int HWT = HW * 2;
    const int j0 = (rel % nj) * 64;
    const int c0 = ((rel / nj) & 3) * 64;
    const int b  = rel / (nj * 4);
    __shared__ float tile[64][65];
    {
        const int tj = threadIdx.x & 63;
        const int tcb = threadIdx.x >> 6;
        const float* fb = f + (size_t)(b * 256 + c0) * HWT + j0;
#pragma unroll
        for (int i = 0; i < 16; ++i) {
            int cl = tcb + i * 4;
            tile[cl][tj] = fb[(size_t)cl * HWT + tj];
        }
    }
    __syncthreads();
    {
        const int tc = threadIdx.x & 63;
        const int tjb = threadIdx.x >> 6;
#pragma unroll
        for (int i = 0; i < 16; ++i) {
            int jl = tjb + i * 4;
            int j = j0 + jl;
            int p = j >> 1, t = j & 1;
            int row = rowbase + (b * 2 + t) * HW + p;
            XP[(size_t)row * 256 + c0 + tc] = __float2bfloat16(tile[tc][jl]);
        }
    }
}

// ---------------- K2: all weight transposes + bias concat in ONE launch ----
__global__ __launch_bounds__(256) void wtrans_all_kernel(const float* __restrict__ Wq,
                                                         const float* __restrict__ Wv,
                                                         const float* __restrict__ Woff,
                                                         const float* __restrict__ Wattn,
                                                         const float* __restrict__ Wout,
                                                         const float* __restrict__ boff,
                                                         const float* __restrict__ battn,
                                                         __hip_bfloat16* __restrict__ WTvq,
                                                         __hip_bfloat16* __restrict__ WToa,
                                                         __hip_bfloat16* __restrict__ WTout,
                                                         float* __restrict__ bias_oa) {
    __shared__ float t[32][33];
    const int bx = blockIdx.x;
    const int tid = threadIdx.x;
    if (bx == 288) {
        bias_oa[tid] = boff[tid];
        if (tid < 128) bias_oa[256 + tid] = battn[tid];
        return;
    }
    const float* W; __hip_bfloat16* WT; int N; int rel;
    if (bx < 64)       { W = Wv;    WT = WTvq;             N = 256; rel = bx; }
    else if (bx < 128) { W = Wq;    WT = WTvq + 256 * 256; N = 256; rel = bx - 64; }
    else if (bx < 192) { W = Woff;  WT = WToa;             N = 256; rel = bx - 128; }
    else if (bx < 224) { W = Wattn; WT = WToa + 256 * 256; N = 128; rel = bx - 192; }
    else               { W = Wout;  WT = WTout;            N = 256; rel = bx - 224; }
    const int K = 256;
    const int ntiles = N >> 5;
    const int n0 = (rel % ntiles) * 32, k0 = (rel / ntiles) * 32;
    const int c = tid & 31, r = tid >> 5;
#pragma unroll
    for (int i = 0; i < 4; ++i)
        t[r + 8 * i][c] = W[(size_t)(k0 + r + 8 * i) * N + n0 + c];
    __syncthreads();
#pragma unroll
    for (int i = 0; i < 4; ++i)
        WT[(size_t)(n0 + r + 8 * i) * K + k0 + c] = __float2bfloat16(t[c][r + 8 * i]);
}

// ---------------- K3: bf16 MFMA GEMM  C = A[M,K] @ BT[N,K]^T + bias --------
// OUTMODE: 0 = f32 single ; 1 = dual bf16 split at col 256 ; 2 = f32 scatter
template <int OUTMODE>
__global__ __launch_bounds__(256) void gemm_mfma(const __hip_bfloat16* __restrict__ A,
                                                 const __hip_bfloat16* __restrict__ BT,
                                                 const float* __restrict__ bias,
                                                 const float* __restrict__ bias2,
                                                 void* __restrict__ Cout,
                                                 void* __restrict__ Cout2,
                                                 int M, int N, int K) {
    __shared__ __align__(16) __hip_bfloat16 As[64][72];
    __shared__ __align__(16) __hip_bfloat16 Bs[64][72];
    const int m0 = blockIdx.x * 64;
    const int n0 = blockIdx.y * 64;
    const int w = threadIdx.x >> 6;
    const int lane = threadIdx.x & 63;
    const int wm = (w >> 1) * 32;
    const int wn = (w & 1) * 32;
    const int fr = lane & 15;
    const int fq = lane >> 4;
    const int srow = threadIdx.x >> 3;
    const int schunk = threadIdx.x & 7;
    f32x4 acc[2][2] = {};

    for (int kt = 0; kt < K; kt += 64) {
        __syncthreads();
#pragma unroll
        for (int i = 0; i < 2; ++i) {
            int r = srow + 32 * i;
            float4 va = *(const float4*)(&A[(size_t)(m0 + r) * K + kt + schunk * 8]);
            *(float4*)(&As[r][schunk * 8]) = va;
            float4 vb = *(const float4*)(&BT[(size_t)(n0 + r) * K + kt + schunk * 8]);
            *(float4*)(&Bs[r][schunk * 8]) = vb;
        }
        __syncthreads();
#pragma unroll
        for (int ks = 0; ks < 2; ++ks) {
            short8 a[2], b[2];
#pragma unroll
            for (int fi = 0; fi < 2; ++fi)
                a[fi] = *(const short8*)(&As[wm + fi * 16 + fr][ks * 32 + fq * 8]);
#pragma unroll
            for (int fj = 0; fj < 2; ++fj)
                b[fj] = *(const short8*)(&Bs[wn + fj * 16 + fr][ks * 32 + fq * 8]);
#pragma unroll
            for (int fi = 0; fi < 2; ++fi)
#pragma unroll
                for (int fj = 0; fj < 2; ++fj)
                    acc[fi][fj] = __builtin_amdgcn_mfma_f32_16x16x32_bf16(
                        a[fi], b[fj], acc[fi][fj], 0, 0, 0);
        }
    }

    if (OUTMODE == 2) {
        const int lvl = level_of_row(m0);
        const int qbase[4]   = {0, 16384, 20480, 21504};
        const int wtab[4]    = {64, 32, 16, 8};
        const size_t obase[4] = {0, 4194304, 5242880, 5505024};
        const int Wl = wtab[lvl];
        const int HW = Wl * Wl;
        float* out = (float*)Cout;
#pragma unroll
        for (int fi = 0; fi < 2; ++fi)
#pragma unroll
            for (int fj = 0; fj < 2; ++fj) {
                int col = n0 + wn + fj * 16 + fr;
                float bb = bias[col];
#pragma unroll
                for (int r = 0; r < 4; ++r) {
                    int row = m0 + wm + fi * 16 + fq * 4 + r;
                    int r2 = row - qbase[lvl];
                    int bt = r2 / HW;
                    int p  = r2 - bt * HW;
                    int b  = bt >> 1, t = bt & 1;
                    int y  = p / Wl, x = p - y * Wl;
                    size_t addr = obase[lvl] +
                        ((((size_t)b * 256 + col) * Wl + y) * Wl + x) * 2 + t;
                    out[addr] = acc[fi][fj][r] + bb;
                }
            }
    } else if (OUTMODE == 1) {
        __hip_bfloat16* dst; const float* bs; int cb;
        if (n0 < 256) { dst = (__hip_bfloat16*)Cout;  bs = bias;  cb = n0; }
        else          { dst = (__hip_bfloat16*)Cout2; bs = bias2; cb = n0 - 256; }
#pragma unroll
        for (int fi = 0; fi < 2; ++fi)
#pragma unroll
            for (int fj = 0; fj < 2; ++fj) {
                int col = cb + wn + fj * 16 + fr;
                float bb = bs[col];
#pragma unroll
                for (int r = 0; r < 4; ++r) {
                    int row = m0 + wm + fi * 16 + fq * 4 + r;
                    dst[(size_t)row * 256 + col] = __float2bfloat16(acc[fi][fj][r] + bb);
                }
            }
    } else {
#pragma unroll
        for (int fi = 0; fi < 2; ++fi)
#pragma unroll
            for (int fj = 0; fj < 2; ++fj) {
                int col = n0 + wn + fj * 16 + fr;
                float bb = bias[col];
#pragma unroll
                for (int r = 0; r < 4; ++r) {
                    int row = m0 + wm + fi * 16 + fq * 4 + r;
                    ((float*)Cout)[(size_t)row * N + col] = acc[fi][fj][r] + bb;
                }
            }
    }
}

// ---------------- K5: sampling: fused softmax + taps + bf16 gather ---------
// Split tap storage: int4 offsets + float4 weights, [q][t][h] layout.
// Phase-2 tap loop: #pragma unroll 2 -> ~8 outstanding loads, small live set
// so the allocator can land <=64 VGPR (8 waves/SIMD) WITHOUT spilling.
__device__ __forceinline__ void accum(f32x4& acc, uint2 u, float w) {
    acc[0] = fmaf(w, __uint_as_float(u.x << 16), acc[0]);
    acc[1] = fmaf(w, __uint_as_float(u.x & 0xffff0000u), acc[1]);
    acc[2] = fmaf(w, __uint_as_float(u.y << 16), acc[2]);
    acc[3] = fmaf(w, __uint_as_float(u.y & 0xffff0000u), acc[3]);
}

#define QB 4
__global__ __launch_bounds__(256, 2) void sample_kernel(const __hip_bfloat16* __restrict__ VAL,
                                                        const float* __restrict__ OA,
                                                        __hip_bfloat16* __restrict__ SAMP) {
    __shared__ int4   toff[QB * 16 * 8];   // [q][t(16)][h(8)]
    __shared__ float4 twgt[QB * 16 * 8];
    const int R0 = blockIdx.x * QB;
    const int tid = threadIdx.x;
    const int qbase[4] = {0, 16384, 20480, 21504};
    const int wtab[4]  = {64, 32, 16, 8};

    // ---- phase 1: per-(q,h) softmax over 16 + tap precompute (128 threads) ----
    if (tid < QB * 32) {
        const int qh = tid >> 2, part = tid & 3;   // 4 threads per (q,h), 4 taps each
        const int q = qh >> 3, h = qh & 7;
        const int R = R0 + q;
        const int lq = level_of_row(R);
        const int Wq_ = wtab[lq];
        const int r2 = R - qbase[lq];
        const int bt = r2 / (Wq_ * Wq_);
        const int p  = r2 - bt * (Wq_ * Wq_);
        const float refx = ((p % Wq_) + 0.5f) / (float)Wq_;
        const float refy = ((p / Wq_) + 0.5f) / (float)Wq_;
        const float* oarow = OA + (size_t)R * 384;
        float4 offA = *(const float4*)(oarow + h * 32 + part * 8);
        float4 offB = *(const float4*)(oarow + h * 32 + part * 8 + 4);
        float4 awv  = *(const float4*)(oarow + 256 + h * 16 + part * 4);
        // softmax across the 4-lane group (16 taps of this (q,h))
        float m = fmaxf(fmaxf(awv.x, awv.y), fmaxf(awv.z, awv.w));
        m = fmaxf(m, __shfl_xor(m, 1));
        m = fmaxf(m, __shfl_xor(m, 2));
        float e0 = __expf(awv.x - m), e1 = __expf(awv.y - m);
        float e2 = __expf(awv.z - m), e3 = __expf(awv.w - m);
        float s = e0 + e1 + e2 + e3;
        s += __shfl_xor(s, 1);
        s += __shfl_xor(s, 2);
        const float inv = 1.0f / s;
        const int l = part;                // this thread's 4 taps are all level part
        const int Wl = wtab[l];
        const float invWf = 1.0f / (float)Wl;
        const int base = (qbase[l] + bt * Wl * Wl) * 256;
        float oxy[8] = {offA.x, offA.y, offA.z, offA.w, offB.x, offB.y, offB.z, offB.w};
        float ee[4] = {e0, e1, e2, e3};
#pragma unroll
        for (int i = 0; i < 4; ++i) {
            float ox = oxy[2 * i], oy = oxy[2 * i + 1];
            float aw = ee[i] * inv;
            float lx = fminf(fmaxf(refx + ox * invWf, 0.f), 1.f);
            float ly = fminf(fmaxf(refy + oy * invWf, 0.f), 1.f);
            float px = lx * Wl - 0.5f;
            float py = ly * Wl - 0.5f;
            float x0f = floorf(px), y0f = floorf(py);
            int x0 = (int)x0f, y0 = (int)y0f;
            float wx = px - x0f, wy = py - y0f;
            float vx0 = (x0 >= 0) ? 1.f : 0.f;
            float vx1 = (x0 + 1 <= Wl - 1) ? 1.f : 0.f;
            float vy0 = (y0 >= 0) ? 1.f : 0.f;
            float vy1 = (y0 + 1 <= Wl - 1) ? 1.f : 0.f;
            int x0c = max(x0, 0), x1c = min(x0 + 1, Wl - 1);
            int y0c = max(y0, 0), y1c = min(y0 + 1, Wl - 1);
            int idx = (q * 16 + part * 4 + i) * 8 + h;
            toff[idx] = make_int4(base + (y0c * Wl + x0c) * 256,
                                  base + (y0c * Wl + x1c) * 256,
                                  base + (y1c * Wl + x0c) * 256,
                                  base + (y1c * Wl + x1c) * 256);
            float4 w4;
            w4.x = aw * (1.f - wx) * (1.f - wy) * vx0 * vy0;
            w4.y = aw * wx * (1.f - wy) * vx1 * vy0;
            w4.z = aw * (1.f - wx) * wy * vx0 * vy1;
            w4.w = aw * wx * wy * vx1 * vy1;
            twgt[idx] = w4;
        }
    }
    __syncthreads();

    // ---- phase 2: one wave per query; lane = (head, d4); bf16 uint2 gathers ----
    const int wv = tid >> 6, lane = tid & 63;
    const int h = lane >> 3, d4 = lane & 7;
    const int R = R0 + wv;
    const __hip_bfloat16* vb = VAL + h * 32 + d4 * 4;
    const int4*   to = &toff[wv * 128];
    const float4* tw = &twgt[wv * 128];
    f32x4 acc = {0.f, 0.f, 0.f, 0.f};
#pragma unroll 2
    for (int t = 0; t < 16; ++t) {
        int4   o  = to[t * 8 + h];
        float4 w4 = tw[t * 8 + h];
        uint2 v00 = *(const uint2*)(vb + o.x);
        uint2 v10 = *(const uint2*)(vb + o.y);
        uint2 v01 = *(const uint2*)(vb + o.z);
        uint2 v11 = *(const uint2*)(vb + o.w);
        accum(acc, v00, w4.x);
        accum(acc, v10, w4.y);
        accum(acc, v01, w4.z);
        accum(acc, v11, w4.w);
    }
    union { ushort u[4]; ushort4 v4; } sa;
#pragma unroll
    for (int i = 0; i < 4; ++i) {
        __hip_bfloat16 ba = __float2bfloat16(acc[i]);
        sa.u[i] = *(ushort*)&ba;
    }
    *(ushort4*)(&SAMP[(size_t)R * 256 + h * 32 + d4 * 4]) = sa.v4;
}

// ---------------- launch ---------------------------------------------------
extern "C" void kernel_launch(void* const* d_in, const int* in_sizes, int n_in,
                              void* d_out, int out_size, void* d_ws, size_t ws_size,
                              hipStream_t stream) {
    (void)in_sizes; (void)n_in; (void)out_size; (void)ws_size;
    const float* f0 = (const float*)d_in[0];
    const float* f1 = (const float*)d_in[1];
    const float* f2 = (const float*)d_in[2];
    const float* f3 = (const float*)d_in[3];
    const float* Wq    = (const float*)d_in[4];
    const float* bq    = (const float*)d_in[5];
    const float* Wv    = (const float*)d_in[6];
    const float* bv    = (const float*)d_in[7];
    const float* Woff  = (const float*)d_in[8];
    const float* boff  = (const float*)d_in[9];
    const float* Wattn = (const float*)d_in[10];
    const float* battn = (const float*)d_in[11];
    const float* Wout  = (const float*)d_in[12];
    const float* bout  = (const float*)d_in[13];
    float* out = (float*)d_out;

    char* w = (char*)d_ws;
    __hip_bfloat16* XPb   = (__hip_bfloat16*)w;   w += (size_t)NR * 256 * 2;
    __hip_bfloat16* Qb    = (__hip_bfloat16*)w;   w += (size_t)NR * 256 * 2;
    __hip_bfloat16* SAMPb = (__hip_bfloat16*)w;   w += (size_t)NR * 256 * 2;
    __hip_bfloat16* VAL   = (__hip_bfloat16*)w;   w += (size_t)NR * 256 * 2;
    float* OA   = (float*)w;                      w += (size_t)NR * 384 * 4;   // [OFF(256)|ATT(128)]
    __hip_bfloat16* WTvq  = (__hip_bfloat16*)w;   w += 512 * 256 * 2;          // [Wv^T | Wq^T]
    __hip_bfloat16* WToa  = (__hip_bfloat16*)w;   w += 384 * 256 * 2;          // [Woff^T | Wattn^T]
    __hip_bfloat16* WTout = (__hip_bfloat16*)w;   w += 256 * 256 * 2;
    float* bias_oa = (float*)w;                   w += 384 * 4;

    // K1: pack all levels (1 launch)
    hipLaunchKernelGGL(pack_all_kernel, dim3(1360), dim3(256), 0, stream, f0, f1, f2, f3, XPb);

    // K2: all weight transposes + bias concat (1 launch)
    hipLaunchKernelGGL(wtrans_all_kernel, dim3(289), dim3(256), 0, stream,
                       Wq, Wv, Woff, Wattn, Wout, boff, battn, WTvq, WToa, WTout, bias_oa);

    // K3a: fused VAL+Q projection (N=512, dual bf16 outputs)
    hipLaunchKernelGGL((gemm_mfma<1>), dim3(NR / 64, 8), dim3(256), 0, stream,
                       XPb, WTvq, bv, bq, (void*)VAL, (void*)Qb, NR, 512, 256);

    // K3b: OFF+ATT projection (N=384, f32)
    hipLaunchKernelGGL((gemm_mfma<0>), dim3(NR / 64, 6), dim3(256), 0, stream,
                       Qb, WToa, bias_oa, nullptr, (void*)OA, nullptr, NR, 384, 256);

    // K5: sampling (fused softmax + taps + bf16 gather)
    hipLaunchKernelGGL(sample_kernel, dim3(NR / QB), dim3(256), 0, stream, VAL, OA, SAMPb);

    // K6: output projection + scatter
    hipLaunchKernelGGL((gemm_mfma<2>), dim3(NR / 64, 4), dim3(256), 0, stream,
                       SAMPb, WTout, bout, nullptr, (void*)out, nullptr, NR, 256, 256);
}